// Round 9
// baseline (370.089 us; speedup 1.0000x reference)
//
#include <hip/hip_runtime.h>
#include <hip/hip_bf16.h>

#define B_  2
#define T_  2048
#define D_  2048
#define H_  16
#define HD_ 128
#define NT_ 4096   // B*T
#define D3_ 6144   // 3*D

typedef __bf16 bf16;
typedef _Float16 f16;
typedef bf16 bf16x2 __attribute__((ext_vector_type(2)));
typedef bf16 bf16x4 __attribute__((ext_vector_type(4)));
typedef bf16 bf16x8 __attribute__((ext_vector_type(8)));
typedef f16  f16x2  __attribute__((ext_vector_type(2)));
typedef f16  f16x4  __attribute__((ext_vector_type(4)));
typedef float floatx4 __attribute__((ext_vector_type(4)));

__device__ __forceinline__ void gl_lds16(const void* g, void* l) {
    __builtin_amdgcn_global_load_lds((const __attribute__((address_space(1))) void*)g,
                                     (__attribute__((address_space(3))) void*)l, 16, 0, 0);
}

// ---------------- fused prep: x->bf16, Wqkv^T->bf16, Wproj^T->bf16 ----------------
__global__ __launch_bounds__(256) void k_prep(const float* __restrict__ x,
                                              const float* __restrict__ Wqkv, const float* __restrict__ Wproj,
                                              bf16* __restrict__ xb, bf16* __restrict__ WqkvT, bf16* __restrict__ WprojT) {
    int blk = blockIdx.x;
    int tid = threadIdx.x;
    if (blk < 8192) {   // x convert: 8192*256*4 = 8M elems
        int i = blk * 256 + tid;
        float4 v = ((const float4*)x)[i];
        bf16x4 o = { (bf16)v.x, (bf16)v.y, (bf16)v.z, (bf16)v.w };
        ((bf16x4*)xb)[i] = o;
        return;
    }
    __shared__ float tile[64][65];
    const float* in; bf16* out; int C, bx;
    if (blk < 8192 + 3072) { bx = blk - 8192; in = Wqkv; out = WqkvT; C = D3_; }
    else                   { bx = blk - 8192 - 3072; in = Wproj; out = WprojT; C = D_; }
    const int R = D_;
    int nbx = C / 64;
    int c0 = (bx % nbx) * 64, r0 = (bx / nbx) * 64;
#pragma unroll
    for (int i = 0; i < 16; i++) {
        int idx = tid + i * 256, r = idx >> 6, c = idx & 63;
        tile[r][c] = in[(size_t)(r0 + r) * C + (c0 + c)];
    }
    __syncthreads();
#pragma unroll
    for (int i = 0; i < 16; i++) {
        int idx = tid + i * 256, r = idx >> 6, c = idx & 63;
        out[(size_t)(c0 + r) * R + (r0 + c)] = (bf16)tile[c][r];
    }
}

// ---------------- QKV GEMM: 256x128 tile, BK=64, 8 waves, TRIPLE-buffered counted-vmcnt pipeline (R7, proven) ----------------
__global__ __launch_bounds__(512, 1) void k_gemm_qkv(const bf16* __restrict__ A, const bf16* __restrict__ Bt,
                                                     const float* __restrict__ cosp, const float* __restrict__ sinp,
                                                     bf16* __restrict__ Qg, bf16* __restrict__ Kg, f16* __restrict__ VTg) {
    __shared__ bf16 smem[3 * 24576];            // 147,456 B
    const int tid = threadIdx.x, wid = tid >> 6, lane = tid & 63;
    const int quad = lane >> 4, l16 = lane & 15;
    const int n0 = blockIdx.x * 128, m0 = blockIdx.y * 256;
    const int wr = (wid >> 1) * 64, wc = (wid & 1) * 64;   // wave tile: 64x64 at (wr, wc)
    const bf16* Ablk = A + (size_t)m0 * D_;
    const bf16* Bblk = Bt + (size_t)n0 * D_;
    const int sgch = (lane & 7) ^ (lane >> 3);
    const int aHalf = (wid >> 2) * 8192;
    const int rAbase = ((wid >> 1) & 1) * 64;
    const int coA = (rAbase + l16) * 64;
    const int coB = 16384 + (wc + l16) * 64;
    floatx4 acc[4][4] = {};

#define QKV_STAGE(KT, BUFO, JJ) do {                                                    \
        int cI_ = (JJ) * 512 + wid * 64 + lane;                                         \
        const bf16* gsrc_;                                                              \
        if ((JJ) < 4) gsrc_ = Ablk + (size_t)(cI_ >> 3) * D_ + (KT) * 64 + sgch * 8;    \
        else          gsrc_ = Bblk + (size_t)((cI_ >> 3) - 256) * D_ + (KT) * 64 + sgch * 8; \
        gl_lds16(gsrc_, smem + (BUFO) + ((JJ) * 512 + wid * 64) * 8);                   \
    } while (0)

#pragma unroll
    for (int j = 0; j < 6; j++) QKV_STAGE(0, 0, j);
#pragma unroll
    for (int j = 0; j < 6; j++) QKV_STAGE(1, 24576, j);
    asm volatile("s_waitcnt vmcnt(6)" ::: "memory");
    __builtin_amdgcn_s_barrier();

    int bcur = 0, bpre = 2;
    for (int t = 0; t < 32; t++) {
        const int bb = bcur * 24576;
        const int po = bpre * 24576;
        const int kpre = t + 2;
        const bool dopre = (kpre < 32);
        bf16x8 af[4][2], bfr0[2][2];
#pragma unroll
        for (int mt = 0; mt < 4; mt++)
#pragma unroll
            for (int kc = 0; kc < 2; kc++)
                af[mt][kc] = *(const bf16x8*)(smem + bb + aHalf + coA + mt * 1024 + (((kc * 4 + quad) ^ (l16 & 7)) * 8));
#pragma unroll
        for (int nt = 0; nt < 2; nt++)
#pragma unroll
            for (int kc = 0; kc < 2; kc++)
                bfr0[nt][kc] = *(const bf16x8*)(smem + bb + coB + nt * 1024 + (((kc * 4 + quad) ^ (l16 & 7)) * 8));
        if (dopre) { QKV_STAGE(kpre, po, 0); QKV_STAGE(kpre, po, 1); QKV_STAGE(kpre, po, 4); }
        __builtin_amdgcn_s_barrier();
        __builtin_amdgcn_s_setprio(1);
#pragma unroll
        for (int mt = 0; mt < 4; mt++)
#pragma unroll
            for (int nt = 0; nt < 2; nt++)
#pragma unroll
                for (int kc = 0; kc < 2; kc++)
                    acc[mt][nt] = __builtin_amdgcn_mfma_f32_16x16x32_bf16(af[mt][kc], bfr0[nt][kc], acc[mt][nt], 0, 0, 0);
        __builtin_amdgcn_s_setprio(0);
        __builtin_amdgcn_s_barrier();
        bf16x8 bfr1[2][2];
#pragma unroll
        for (int nt = 0; nt < 2; nt++)
#pragma unroll
            for (int kc = 0; kc < 2; kc++)
                bfr1[nt][kc] = *(const bf16x8*)(smem + bb + coB + (nt + 2) * 1024 + (((kc * 4 + quad) ^ (l16 & 7)) * 8));
        if (dopre) { QKV_STAGE(kpre, po, 2); QKV_STAGE(kpre, po, 3); QKV_STAGE(kpre, po, 5); }
        __builtin_amdgcn_s_barrier();
        __builtin_amdgcn_s_setprio(1);
#pragma unroll
        for (int mt = 0; mt < 4; mt++)
#pragma unroll
            for (int nt = 0; nt < 2; nt++)
#pragma unroll
                for (int kc = 0; kc < 2; kc++)
                    acc[mt][nt + 2] = __builtin_amdgcn_mfma_f32_16x16x32_bf16(af[mt][kc], bfr1[nt][kc], acc[mt][nt + 2], 0, 0, 0);
        __builtin_amdgcn_s_setprio(0);
        if (t == 30) asm volatile("s_waitcnt vmcnt(0)" ::: "memory");
        else         asm volatile("s_waitcnt vmcnt(6)" ::: "memory");
        __builtin_amdgcn_s_barrier();
        bcur = (bcur == 2) ? 0 : bcur + 1;
        bpre = (bpre == 2) ? 0 : bpre + 1;
    }
#undef QKV_STAGE

    bf16* const stage = smem;                   // [256][130]
#pragma unroll
    for (int mt = 0; mt < 4; mt++)
#pragma unroll
        for (int nt = 0; nt < 4; nt++)
#pragma unroll
            for (int r = 0; r < 4; r++)
                stage[(wr + mt * 16 + quad * 4 + r) * 130 + wc + nt * 16 + l16] = (bf16)acc[mt][nt][r];
    __syncthreads();
    const int type = n0 >> 11, h = (n0 & 2047) >> 7;
    const int b = m0 >> 11, t0 = m0 & 2047;
    if (type < 2) {
        bf16* out = (type == 0 ? Qg : Kg) + ((size_t)(b * H_ + h) * T_ + t0) * HD_;
#pragma unroll
        for (int it = 0; it < 32; it++) {
            int idx = it * 512 + tid, tl = idx >> 6, i = idx & 63;
            float c = cosp[(t0 + tl) * 64 + i], s = sinp[(t0 + tl) * 64 + i];
            float x1 = (float)stage[tl * 130 + i], x2 = (float)stage[tl * 130 + 64 + i];
            bf16x2 o = { (bf16)(x1 * c - x2 * s), (bf16)(x1 * s + x2 * c) };
            *(bf16x2*)(out + (size_t)tl * HD_ + 2 * i) = o;
        }
    } else {
        f16* out = VTg + (size_t)(b * H_ + h) * HD_ * T_ + t0;
#pragma unroll
        for (int it = 0; it < 32; it++) {
            int idx = it * 512 + tid, d = idx >> 7, tp = (idx & 127) * 2;
            f16x2 o = { (f16)(float)stage[tp * 130 + d], (f16)(float)stage[(tp + 1) * 130 + d] };
            *(f16x2*)(out + (size_t)d * T_ + tp) = o;
        }
    }
}

// ---------------- proj GEMM: triple-buffered counted-vmcnt schedule (R8, proven), direct-store epilogue ----------------
__global__ __launch_bounds__(512, 1) void k_proj(const bf16* __restrict__ A, const bf16* __restrict__ Bt,
                                                 float* __restrict__ C) {
    __shared__ bf16 smem[3 * 24576];            // 147,456 B
    const int tid = threadIdx.x, wid = tid >> 6, lane = tid & 63;
    const int quad = lane >> 4, l16 = lane & 15;
    const int n0 = blockIdx.x * 128, m0 = blockIdx.y * 256;
    const int wr = (wid >> 1) * 64, wc = (wid & 1) * 64;
    const bf16* Ablk = A + (size_t)m0 * D_;
    const bf16* Bblk = Bt + (size_t)n0 * D_;
    const int sgch = (lane & 7) ^ (lane >> 3);
    const int aHalf = (wid >> 2) * 8192;
    const int rAbase = ((wid >> 1) & 1) * 64;
    const int coA = (rAbase + l16) * 64;
    const int coB = 16384 + (wc + l16) * 64;
    floatx4 acc[4][4] = {};

#define PRJ_STAGE(KT, BUFO, JJ) do {                                                    \
        int cI_ = (JJ) * 512 + wid * 64 + lane;                                         \
        const bf16* gsrc_;                                                              \
        if ((JJ) < 4) gsrc_ = Ablk + (size_t)(cI_ >> 3) * D_ + (KT) * 64 + sgch * 8;    \
        else          gsrc_ = Bblk + (size_t)((cI_ >> 3) - 256) * D_ + (KT) * 64 + sgch * 8; \
        gl_lds16(gsrc_, smem + (BUFO) + ((JJ) * 512 + wid * 64) * 8);                   \
    } while (0)

#pragma unroll
    for (int j = 0; j < 6; j++) PRJ_STAGE(0, 0, j);
#pragma unroll
    for (int j = 0; j < 6; j++) PRJ_STAGE(1, 24576, j);
    asm volatile("s_waitcnt vmcnt(6)" ::: "memory");
    __builtin_amdgcn_s_barrier();

    int bcur = 0, bpre = 2;
    for (int t = 0; t < 32; t++) {
        const int bb = bcur * 24576;
        const int po = bpre * 24576;
        const int kpre = t + 2;
        const bool dopre = (kpre < 32);
        bf16x8 af[4][2], bfr0[2][2];
#pragma unroll
        for (int mt = 0; mt < 4; mt++)
#pragma unroll
            for (int kc = 0; kc < 2; kc++)
                af[mt][kc] = *(const bf16x8*)(smem + bb + aHalf + coA + mt * 1024 + (((kc * 4 + quad) ^ (l16 & 7)) * 8));
#pragma unroll
        for (int nt = 0; nt < 2; nt++)
#pragma unroll
            for (int kc = 0; kc < 2; kc++)
                bfr0[nt][kc] = *(const bf16x8*)(smem + bb + coB + nt * 1024 + (((kc * 4 + quad) ^ (l16 & 7)) * 8));
        if (dopre) { PRJ_STAGE(kpre, po, 0); PRJ_STAGE(kpre, po, 1); PRJ_STAGE(kpre, po, 4); }
        __builtin_amdgcn_s_barrier();
        __builtin_amdgcn_s_setprio(1);
#pragma unroll
        for (int mt = 0; mt < 4; mt++)
#pragma unroll
            for (int nt = 0; nt < 2; nt++)
#pragma unroll
                for (int kc = 0; kc < 2; kc++)
                    acc[mt][nt] = __builtin_amdgcn_mfma_f32_16x16x32_bf16(af[mt][kc], bfr0[nt][kc], acc[mt][nt], 0, 0, 0);
        __builtin_amdgcn_s_setprio(0);
        __builtin_amdgcn_s_barrier();
        bf16x8 bfr1[2][2];
#pragma unroll
        for (int nt = 0; nt < 2; nt++)
#pragma unroll
            for (int kc = 0; kc < 2; kc++)
                bfr1[nt][kc] = *(const bf16x8*)(smem + bb + coB + (nt + 2) * 1024 + (((kc * 4 + quad) ^ (l16 & 7)) * 8));
        if (dopre) { PRJ_STAGE(kpre, po, 2); PRJ_STAGE(kpre, po, 3); PRJ_STAGE(kpre, po, 5); }
        __builtin_amdgcn_s_barrier();
        __builtin_amdgcn_s_setprio(1);
#pragma unroll
        for (int mt = 0; mt < 4; mt++)
#pragma unroll
            for (int nt = 0; nt < 2; nt++)
#pragma unroll
                for (int kc = 0; kc < 2; kc++)
                    acc[mt][nt + 2] = __builtin_amdgcn_mfma_f32_16x16x32_bf16(af[mt][kc], bfr1[nt][kc], acc[mt][nt + 2], 0, 0, 0);
        __builtin_amdgcn_s_setprio(0);
        if (t == 30) asm volatile("s_waitcnt vmcnt(0)" ::: "memory");
        else         asm volatile("s_waitcnt vmcnt(6)" ::: "memory");
        __builtin_amdgcn_s_barrier();
        bcur = (bcur == 2) ? 0 : bcur + 1;
        bpre = (bpre == 2) ? 0 : bpre + 1;
    }
#undef PRJ_STAGE

#pragma unroll
    for (int mt = 0; mt < 4; mt++)
#pragma unroll
        for (int nt = 0; nt < 4; nt++)
#pragma unroll
            for (int r = 0; r < 4; r++) {
                int row = m0 + wr + mt * 16 + quad * 4 + r;
                int col = n0 + wc + nt * 16 + l16;
                C[(size_t)row * D_ + col] = acc[mt][nt][r];
            }
}

// ---------------- Flash attention (R0 serial form — proven best across 3 containers) ----------------
__global__ __launch_bounds__(256, 2) void k_flash(const bf16* __restrict__ Qg, const bf16* __restrict__ Kg,
                                                  const f16* __restrict__ VTg, bf16* __restrict__ Og) {
    __shared__ bf16 Ksh[64 * 128];      // K tile: 64 t x 128 d, XOR-swizzled 16B chunks
    __shared__ f16  Vsh[128 * 64];      // V^T tile: 128 d x 64 t, XOR-swizzled
    const int b1 = blockIdx.x;
    const int bh = b1 & 31;
    const int qt = (b1 < 256) ? (15 - (b1 >> 5)) : ((b1 - 256) >> 5);
    const int tid = threadIdx.x, w = tid >> 6, lane = tid & 63;
    const int quad = lane >> 4, l16 = lane & 15;
    const float scale2 = 0.08838834764831845f * 1.4426950408889634f;  // (1/sqrt(128))*log2(e)
    const int wrow = w * 32;
    const bf16* Qb = Qg + ((size_t)bh * T_ + qt * 128) * HD_;
    bf16x8 qf[2][4];
#pragma unroll
    for (int mt = 0; mt < 2; mt++)
#pragma unroll
        for (int kc = 0; kc < 4; kc++)
            qf[mt][kc] = *(const bf16x8*)(Qb + (size_t)(wrow + mt * 16 + l16) * HD_ + kc * 32 + quad * 8);
    floatx4 oaccT[8][2] = {};   // [d-tile][q-tile]: col=l16=query, row=quad*4+r=d
    float lsum[2] = { 0.f, 0.f };
    const int nkt = 2 * (qt + 1);
    for (int kt = 0; kt < nkt; kt++) {
        __syncthreads();
        const bf16* Kt = Kg + ((size_t)bh * T_ + kt * 64) * HD_;
        const f16*  Vt = VTg + (size_t)bh * HD_ * T_ + kt * 64;
#pragma unroll
        for (int i = 0; i < 4; i++) {
            int ch = w * 4 + i;
            {
                int row = ch * 4 + (lane >> 4);
                int c = (lane & 15) ^ (row & 7);
                gl_lds16(Kt + (size_t)row * HD_ + c * 8, Ksh + ch * 512);
            }
            {
                int row = ch * 8 + (lane >> 3);
                int c = (lane & 7) ^ (row & 7);
                gl_lds16(Vt + (size_t)row * T_ + c * 8, Vsh + ch * 512);
            }
        }
        __syncthreads();
        const bool diag = (kt >= 2 * qt);
        f16x4 pf[2][4];
#pragma unroll
        for (int nt = 0; nt < 4; nt++) {
            floatx4 s0 = {}, s1 = {};
#pragma unroll
            for (int kc = 0; kc < 4; kc++) {
                bf16x8 kf = *(const bf16x8*)(Ksh + (nt * 16 + l16) * 128 + (((kc * 4 + quad) ^ (l16 & 7)) * 8));
                s0 = __builtin_amdgcn_mfma_f32_16x16x32_bf16(kf, qf[0][kc], s0, 0, 0, 0);
                s1 = __builtin_amdgcn_mfma_f32_16x16x32_bf16(kf, qf[1][kc], s1, 0, 0, 0);
            }
#pragma unroll
            for (int r = 0; r < 4; r++) {
                float v0 = s0[r] * scale2, v1 = s1[r] * scale2;
                if (diag) {
                    int gk = kt * 64 + nt * 16 + quad * 4 + r;
                    if (gk > qt * 128 + wrow + l16) v0 = -1e30f;
                    if (gk > qt * 128 + wrow + 16 + l16) v1 = -1e30f;
                }
                float p0 = exp2f(v0), p1 = exp2f(v1);
                lsum[0] += p0; lsum[1] += p1;
                pf[0][nt][r] = (f16)p0; pf[1][nt][r] = (f16)p1;
            }
        }
        // O^T += V^T P^T  (16x16x16 f16 MFMA)
#pragma unroll
        for (int nt = 0; nt < 4; nt++)
#pragma unroll
            for (int dt = 0; dt < 8; dt++) {
                int row = dt * 16 + l16;
                f16x4 vf = *(const f16x4*)(Vsh + row * 64 + (((nt * 2 + (quad >> 1)) ^ (row & 7)) * 8) + (quad & 1) * 4);
#pragma unroll
                for (int mt = 0; mt < 2; mt++)
                    oaccT[dt][mt] = __builtin_amdgcn_mfma_f32_16x16x16f16(vf, pf[mt][nt], oaccT[dt][mt], 0, 0, 0);
            }
    }
    // epilogue
    const int b = bh >> 4, h = bh & 15;
    float inv[2];
#pragma unroll
    for (int mt = 0; mt < 2; mt++) {
        float l = lsum[mt];
        l += __shfl_xor(l, 16);
        l += __shfl_xor(l, 32);
        inv[mt] = 1.0f / l;
    }
#pragma unroll
    for (int mt = 0; mt < 2; mt++) {
        int t = qt * 128 + wrow + mt * 16 + l16;
#pragma unroll
        for (int dt = 0; dt < 8; dt++) {
            bf16x4 o;
#pragma unroll
            for (int r = 0; r < 4; r++) o[r] = (bf16)(oaccT[dt][mt][r] * inv[mt]);
            int c = h * HD_ + dt * 16 + quad * 4;
            *(bf16x4*)(Og + (size_t)(b * T_ + t) * D_ + c) = o;
        }
    }
}

extern "C" void kernel_launch(void* const* d_in, const int* in_sizes, int n_in,
                              void* d_out, int out_size, void* d_ws, size_t ws_size,
                              hipStream_t stream) {
    const float* x     = (const float*)d_in[0];
    const float* cosp  = (const float*)d_in[1];
    const float* sinp  = (const float*)d_in[2];
    const float* Wqkv  = (const float*)d_in[3];
    const float* Wproj = (const float*)d_in[4];
    float* out = (float*)d_out;
    char* ws = (char*)d_ws;
    // workspace layout (96 MB total)
    bf16* xb     = (bf16*)(ws);                          // 16 MB (reused as O after GEMM1)
    bf16* WqkvT  = (bf16*)(ws + (size_t)(16u << 20));    // 24 MB
    bf16* WprojT = (bf16*)(ws + (size_t)(40u << 20));    //  8 MB
    bf16* Qg     = (bf16*)(ws + (size_t)(48u << 20));    // 16 MB
    bf16* Kg     = (bf16*)(ws + (size_t)(64u << 20));    // 16 MB
    f16*  VTg    = (f16*) (ws + (size_t)(80u << 20));    // 16 MB
    bf16* Og     = xb;

    k_prep<<<dim3(8192 + 3072 + 1024), 256, 0, stream>>>(x, Wqkv, Wproj, xb, WqkvT, WprojT);
    k_gemm_qkv<<<dim3(D3_ / 128, NT_ / 256), 512, 0, stream>>>(xb, WqkvT, cosp, sinp, Qg, Kg, VTg);
    k_flash<<<dim3(512), 256, 0, stream>>>(Qg, Kg, VTg, Og);
    k_proj<<<dim3(D_ / 128, NT_ / 256), 512, 0, stream>>>(Og, WprojT, out);
}

// Round 10
// 357.199 us; speedup vs baseline: 1.0361x; 1.0361x over previous
//
#include <hip/hip_runtime.h>
#include <hip/hip_bf16.h>

#define B_  2
#define T_  2048
#define D_  2048
#define H_  16
#define HD_ 128
#define NT_ 4096   // B*T
#define D3_ 6144   // 3*D

typedef __bf16 bf16;
typedef _Float16 f16;
typedef bf16 bf16x2 __attribute__((ext_vector_type(2)));
typedef bf16 bf16x4 __attribute__((ext_vector_type(4)));
typedef bf16 bf16x8 __attribute__((ext_vector_type(8)));
typedef f16  f16x2  __attribute__((ext_vector_type(2)));
typedef f16  f16x4  __attribute__((ext_vector_type(4)));
typedef float floatx4 __attribute__((ext_vector_type(4)));

__device__ __forceinline__ void gl_lds16(const void* g, void* l) {
    __builtin_amdgcn_global_load_lds((const __attribute__((address_space(1))) void*)g,
                                     (__attribute__((address_space(3))) void*)l, 16, 0, 0);
}

// ---------------- fused prep: x->bf16, Wqkv^T->bf16, Wproj^T->bf16 ----------------
__global__ __launch_bounds__(256) void k_prep(const float* __restrict__ x,
                                              const float* __restrict__ Wqkv, const float* __restrict__ Wproj,
                                              bf16* __restrict__ xb, bf16* __restrict__ WqkvT, bf16* __restrict__ WprojT) {
    int blk = blockIdx.x;
    int tid = threadIdx.x;
    if (blk < 8192) {   // x convert: 8192*256*4 = 8M elems
        int i = blk * 256 + tid;
        float4 v = ((const float4*)x)[i];
        bf16x4 o = { (bf16)v.x, (bf16)v.y, (bf16)v.z, (bf16)v.w };
        ((bf16x4*)xb)[i] = o;
        return;
    }
    __shared__ float tile[64][65];
    const float* in; bf16* out; int C, bx;
    if (blk < 8192 + 3072) { bx = blk - 8192; in = Wqkv; out = WqkvT; C = D3_; }
    else                   { bx = blk - 8192 - 3072; in = Wproj; out = WprojT; C = D_; }
    const int R = D_;
    int nbx = C / 64;
    int c0 = (bx % nbx) * 64, r0 = (bx / nbx) * 64;
#pragma unroll
    for (int i = 0; i < 16; i++) {
        int idx = tid + i * 256, r = idx >> 6, c = idx & 63;
        tile[r][c] = in[(size_t)(r0 + r) * C + (c0 + c)];
    }
    __syncthreads();
#pragma unroll
    for (int i = 0; i < 16; i++) {
        int idx = tid + i * 256, r = idx >> 6, c = idx & 63;
        out[(size_t)(c0 + r) * R + (r0 + c)] = (bf16)tile[c][r];
    }
}

// ---------------- QKV GEMM: 256x128, BK=64, triple-buffered counted-vmcnt, ONE barrier per K-tile ----------------
// Invariant at loop top (post prior vmcnt(6)+barrier): buf[t] fully landed.
// Per iter: read all 16 frags from buf[t]; issue 6 loads for t+2 into buf[(t+2)%3]
// (last read in iter t-1, completed before prior barrier); 32 MFMA; vmcnt(6) lands
// t+1's 6 oldest (t+2's 6 stay in flight); barrier. Tail t=30 -> vmcnt(0).
__global__ __launch_bounds__(512, 1) void k_gemm_qkv(const bf16* __restrict__ A, const bf16* __restrict__ Bt,
                                                     const float* __restrict__ cosp, const float* __restrict__ sinp,
                                                     bf16* __restrict__ Qg, bf16* __restrict__ Kg, f16* __restrict__ VTg) {
    __shared__ bf16 smem[3 * 24576];            // 147,456 B
    const int tid = threadIdx.x, wid = tid >> 6, lane = tid & 63;
    const int quad = lane >> 4, l16 = lane & 15;
    const int n0 = blockIdx.x * 128, m0 = blockIdx.y * 256;
    const int wr = (wid >> 1) * 64, wc = (wid & 1) * 64;   // wave tile: 64x64 at (wr, wc)
    const bf16* Ablk = A + (size_t)m0 * D_;
    const bf16* Bblk = Bt + (size_t)n0 * D_;
    const int sgch = (lane & 7) ^ (lane >> 3);
    const int aHalf = (wid >> 2) * 8192;
    const int rAbase = ((wid >> 1) & 1) * 64;
    const int coA = (rAbase + l16) * 64;
    const int coB = 16384 + (wc + l16) * 64;
    floatx4 acc[4][4] = {};

#define QKV_STAGE(KT, BUFO, JJ) do {                                                    \
        int cI_ = (JJ) * 512 + wid * 64 + lane;                                         \
        const bf16* gsrc_;                                                              \
        if ((JJ) < 4) gsrc_ = Ablk + (size_t)(cI_ >> 3) * D_ + (KT) * 64 + sgch * 8;    \
        else          gsrc_ = Bblk + (size_t)((cI_ >> 3) - 256) * D_ + (KT) * 64 + sgch * 8; \
        gl_lds16(gsrc_, smem + (BUFO) + ((JJ) * 512 + wid * 64) * 8);                   \
    } while (0)

#pragma unroll
    for (int j = 0; j < 6; j++) QKV_STAGE(0, 0, j);
#pragma unroll
    for (int j = 0; j < 6; j++) QKV_STAGE(1, 24576, j);
    asm volatile("s_waitcnt vmcnt(6)" ::: "memory");
    __builtin_amdgcn_s_barrier();

    int bcur = 0, bpre = 2;
    for (int t = 0; t < 32; t++) {
        const int bb = bcur * 24576;
        const int po = bpre * 24576;
        const int kpre = t + 2;
        const bool dopre = (kpre < 32);
        // read ALL fragments for this K-tile (compiler inserts fine-grained lgkmcnt before MFMA use)
        bf16x8 af[4][2], bfr[4][2];
#pragma unroll
        for (int mt = 0; mt < 4; mt++)
#pragma unroll
            for (int kc = 0; kc < 2; kc++)
                af[mt][kc] = *(const bf16x8*)(smem + bb + aHalf + coA + mt * 1024 + (((kc * 4 + quad) ^ (l16 & 7)) * 8));
#pragma unroll
        for (int nt = 0; nt < 4; nt++)
#pragma unroll
            for (int kc = 0; kc < 2; kc++)
                bfr[nt][kc] = *(const bf16x8*)(smem + bb + coB + nt * 1024 + (((kc * 4 + quad) ^ (l16 & 7)) * 8));
        // prefetch tile t+2 (targets buffer not referenced this iteration)
        if (dopre) {
            QKV_STAGE(kpre, po, 0); QKV_STAGE(kpre, po, 1); QKV_STAGE(kpre, po, 2);
            QKV_STAGE(kpre, po, 3); QKV_STAGE(kpre, po, 4); QKV_STAGE(kpre, po, 5);
        }
        __builtin_amdgcn_s_setprio(1);
#pragma unroll
        for (int mt = 0; mt < 4; mt++)
#pragma unroll
            for (int nt = 0; nt < 4; nt++)
#pragma unroll
                for (int kc = 0; kc < 2; kc++)
                    acc[mt][nt] = __builtin_amdgcn_mfma_f32_16x16x32_bf16(af[mt][kc], bfr[nt][kc], acc[mt][nt], 0, 0, 0);
        __builtin_amdgcn_s_setprio(0);
        // single boundary: land t+1 (oldest 6), keep t+2 in flight
        if (t == 30) asm volatile("s_waitcnt vmcnt(0)" ::: "memory");
        else         asm volatile("s_waitcnt vmcnt(6)" ::: "memory");
        __builtin_amdgcn_s_barrier();
        bcur = (bcur == 2) ? 0 : bcur + 1;
        bpre = (bpre == 2) ? 0 : bpre + 1;
    }
#undef QKV_STAGE

    bf16* const stage = smem;                   // [256][130]
#pragma unroll
    for (int mt = 0; mt < 4; mt++)
#pragma unroll
        for (int nt = 0; nt < 4; nt++)
#pragma unroll
            for (int r = 0; r < 4; r++)
                stage[(wr + mt * 16 + quad * 4 + r) * 130 + wc + nt * 16 + l16] = (bf16)acc[mt][nt][r];
    __syncthreads();
    const int type = n0 >> 11, h = (n0 & 2047) >> 7;
    const int b = m0 >> 11, t0 = m0 & 2047;
    if (type < 2) {
        bf16* out = (type == 0 ? Qg : Kg) + ((size_t)(b * H_ + h) * T_ + t0) * HD_;
#pragma unroll
        for (int it = 0; it < 32; it++) {
            int idx = it * 512 + tid, tl = idx >> 6, i = idx & 63;
            float c = cosp[(t0 + tl) * 64 + i], s = sinp[(t0 + tl) * 64 + i];
            float x1 = (float)stage[tl * 130 + i], x2 = (float)stage[tl * 130 + 64 + i];
            bf16x2 o = { (bf16)(x1 * c - x2 * s), (bf16)(x1 * s + x2 * c) };
            *(bf16x2*)(out + (size_t)tl * HD_ + 2 * i) = o;
        }
    } else {
        f16* out = VTg + (size_t)(b * H_ + h) * HD_ * T_ + t0;
#pragma unroll
        for (int it = 0; it < 32; it++) {
            int idx = it * 512 + tid, d = idx >> 7, tp = (idx & 127) * 2;
            f16x2 o = { (f16)(float)stage[tp * 130 + d], (f16)(float)stage[(tp + 1) * 130 + d] };
            *(f16x2*)(out + (size_t)d * T_ + tp) = o;
        }
    }
}

// ---------------- proj GEMM: same single-barrier triple-buffered schedule, direct-store epilogue ----------------
__global__ __launch_bounds__(512, 1) void k_proj(const bf16* __restrict__ A, const bf16* __restrict__ Bt,
                                                 float* __restrict__ C) {
    __shared__ bf16 smem[3 * 24576];            // 147,456 B
    const int tid = threadIdx.x, wid = tid >> 6, lane = tid & 63;
    const int quad = lane >> 4, l16 = lane & 15;
    const int n0 = blockIdx.x * 128, m0 = blockIdx.y * 256;
    const int wr = (wid >> 1) * 64, wc = (wid & 1) * 64;
    const bf16* Ablk = A + (size_t)m0 * D_;
    const bf16* Bblk = Bt + (size_t)n0 * D_;
    const int sgch = (lane & 7) ^ (lane >> 3);
    const int aHalf = (wid >> 2) * 8192;
    const int rAbase = ((wid >> 1) & 1) * 64;
    const int coA = (rAbase + l16) * 64;
    const int coB = 16384 + (wc + l16) * 64;
    floatx4 acc[4][4] = {};

#define PRJ_STAGE(KT, BUFO, JJ) do {                                                    \
        int cI_ = (JJ) * 512 + wid * 64 + lane;                                         \
        const bf16* gsrc_;                                                              \
        if ((JJ) < 4) gsrc_ = Ablk + (size_t)(cI_ >> 3) * D_ + (KT) * 64 + sgch * 8;    \
        else          gsrc_ = Bblk + (size_t)((cI_ >> 3) - 256) * D_ + (KT) * 64 + sgch * 8; \
        gl_lds16(gsrc_, smem + (BUFO) + ((JJ) * 512 + wid * 64) * 8);                   \
    } while (0)

#pragma unroll
    for (int j = 0; j < 6; j++) PRJ_STAGE(0, 0, j);
#pragma unroll
    for (int j = 0; j < 6; j++) PRJ_STAGE(1, 24576, j);
    asm volatile("s_waitcnt vmcnt(6)" ::: "memory");
    __builtin_amdgcn_s_barrier();

    int bcur = 0, bpre = 2;
    for (int t = 0; t < 32; t++) {
        const int bb = bcur * 24576;
        const int po = bpre * 24576;
        const int kpre = t + 2;
        const bool dopre = (kpre < 32);
        bf16x8 af[4][2], bfr[4][2];
#pragma unroll
        for (int mt = 0; mt < 4; mt++)
#pragma unroll
            for (int kc = 0; kc < 2; kc++)
                af[mt][kc] = *(const bf16x8*)(smem + bb + aHalf + coA + mt * 1024 + (((kc * 4 + quad) ^ (l16 & 7)) * 8));
#pragma unroll
        for (int nt = 0; nt < 4; nt++)
#pragma unroll
            for (int kc = 0; kc < 2; kc++)
                bfr[nt][kc] = *(const bf16x8*)(smem + bb + coB + nt * 1024 + (((kc * 4 + quad) ^ (l16 & 7)) * 8));
        if (dopre) {
            PRJ_STAGE(kpre, po, 0); PRJ_STAGE(kpre, po, 1); PRJ_STAGE(kpre, po, 2);
            PRJ_STAGE(kpre, po, 3); PRJ_STAGE(kpre, po, 4); PRJ_STAGE(kpre, po, 5);
        }
        __builtin_amdgcn_s_setprio(1);
#pragma unroll
        for (int mt = 0; mt < 4; mt++)
#pragma unroll
            for (int nt = 0; nt < 4; nt++)
#pragma unroll
                for (int kc = 0; kc < 2; kc++)
                    acc[mt][nt] = __builtin_amdgcn_mfma_f32_16x16x32_bf16(af[mt][kc], bfr[nt][kc], acc[mt][nt], 0, 0, 0);
        __builtin_amdgcn_s_setprio(0);
        if (t == 30) asm volatile("s_waitcnt vmcnt(0)" ::: "memory");
        else         asm volatile("s_waitcnt vmcnt(6)" ::: "memory");
        __builtin_amdgcn_s_barrier();
        bcur = (bcur == 2) ? 0 : bcur + 1;
        bpre = (bpre == 2) ? 0 : bpre + 1;
    }
#undef PRJ_STAGE

#pragma unroll
    for (int mt = 0; mt < 4; mt++)
#pragma unroll
        for (int nt = 0; nt < 4; nt++)
#pragma unroll
            for (int r = 0; r < 4; r++) {
                int row = m0 + wr + mt * 16 + quad * 4 + r;
                int col = n0 + wc + nt * 16 + l16;
                C[(size_t)row * D_ + col] = acc[mt][nt][r];
            }
}

// ---------------- Flash attention (R0 serial form) ----------------
__global__ __launch_bounds__(256, 2) void k_flash(const bf16* __restrict__ Qg, const bf16* __restrict__ Kg,
                                                  const f16* __restrict__ VTg, bf16* __restrict__ Og) {
    __shared__ bf16 Ksh[64 * 128];      // K tile: 64 t x 128 d, XOR-swizzled 16B chunks
    __shared__ f16  Vsh[128 * 64];      // V^T tile: 128 d x 64 t, XOR-swizzled
    const int b1 = blockIdx.x;
    const int bh = b1 & 31;
    const int qt = (b1 < 256) ? (15 - (b1 >> 5)) : ((b1 - 256) >> 5);
    const int tid = threadIdx.x, w = tid >> 6, lane = tid & 63;
    const int quad = lane >> 4, l16 = lane & 15;
    const float scale2 = 0.08838834764831845f * 1.4426950408889634f;  // (1/sqrt(128))*log2(e)
    const int wrow = w * 32;
    const bf16* Qb = Qg + ((size_t)bh * T_ + qt * 128) * HD_;
    bf16x8 qf[2][4];
#pragma unroll
    for (int mt = 0; mt < 2; mt++)
#pragma unroll
        for (int kc = 0; kc < 4; kc++)
            qf[mt][kc] = *(const bf16x8*)(Qb + (size_t)(wrow + mt * 16 + l16) * HD_ + kc * 32 + quad * 8);
    floatx4 oaccT[8][2] = {};   // [d-tile][q-tile]: col=l16=query, row=quad*4+r=d
    float lsum[2] = { 0.f, 0.f };
    const int nkt = 2 * (qt + 1);
    for (int kt = 0; kt < nkt; kt++) {
        __syncthreads();
        const bf16* Kt = Kg + ((size_t)bh * T_ + kt * 64) * HD_;
        const f16*  Vt = VTg + (size_t)bh * HD_ * T_ + kt * 64;
#pragma unroll
        for (int i = 0; i < 4; i++) {
            int ch = w * 4 + i;
            {
                int row = ch * 4 + (lane >> 4);
                int c = (lane & 15) ^ (row & 7);
                gl_lds16(Kt + (size_t)row * HD_ + c * 8, Ksh + ch * 512);
            }
            {
                int row = ch * 8 + (lane >> 3);
                int c = (lane & 7) ^ (row & 7);
                gl_lds16(Vt + (size_t)row * T_ + c * 8, Vsh + ch * 512);
            }
        }
        __syncthreads();
        const bool diag = (kt >= 2 * qt);
        f16x4 pf[2][4];
#pragma unroll
        for (int nt = 0; nt < 4; nt++) {
            floatx4 s0 = {}, s1 = {};
#pragma unroll
            for (int kc = 0; kc < 4; kc++) {
                bf16x8 kf = *(const bf16x8*)(Ksh + (nt * 16 + l16) * 128 + (((kc * 4 + quad) ^ (l16 & 7)) * 8));
                s0 = __builtin_amdgcn_mfma_f32_16x16x32_bf16(kf, qf[0][kc], s0, 0, 0, 0);
                s1 = __builtin_amdgcn_mfma_f32_16x16x32_bf16(kf, qf[1][kc], s1, 0, 0, 0);
            }
#pragma unroll
            for (int r = 0; r < 4; r++) {
                float v0 = s0[r] * scale2, v1 = s1[r] * scale2;
                if (diag) {
                    int gk = kt * 64 + nt * 16 + quad * 4 + r;
                    if (gk > qt * 128 + wrow + l16) v0 = -1e30f;
                    if (gk > qt * 128 + wrow + 16 + l16) v1 = -1e30f;
                }
                float p0 = exp2f(v0), p1 = exp2f(v1);
                lsum[0] += p0; lsum[1] += p1;
                pf[0][nt][r] = (f16)p0; pf[1][nt][r] = (f16)p1;
            }
        }
        // O^T += V^T P^T  (16x16x16 f16 MFMA)
#pragma unroll
        for (int nt = 0; nt < 4; nt++)
#pragma unroll
            for (int dt = 0; dt < 8; dt++) {
                int row = dt * 16 + l16;
                f16x4 vf = *(const f16x4*)(Vsh + row * 64 + (((nt * 2 + (quad >> 1)) ^ (row & 7)) * 8) + (quad & 1) * 4);
#pragma unroll
                for (int mt = 0; mt < 2; mt++)
                    oaccT[dt][mt] = __builtin_amdgcn_mfma_f32_16x16x16f16(vf, pf[mt][nt], oaccT[dt][mt], 0, 0, 0);
            }
    }
    // epilogue
    const int b = bh >> 4, h = bh & 15;
    float inv[2];
#pragma unroll
    for (int mt = 0; mt < 2; mt++) {
        float l = lsum[mt];
        l += __shfl_xor(l, 16);
        l += __shfl_xor(l, 32);
        inv[mt] = 1.0f / l;
    }
#pragma unroll
    for (int mt = 0; mt < 2; mt++) {
        int t = qt * 128 + wrow + mt * 16 + l16;
#pragma unroll
        for (int dt = 0; dt < 8; dt++) {
            bf16x4 o;
#pragma unroll
            for (int r = 0; r < 4; r++) o[r] = (bf16)(oaccT[dt][mt][r] * inv[mt]);
            int c = h * HD_ + dt * 16 + quad * 4;
            *(bf16x4*)(Og + (size_t)(b * T_ + t) * D_ + c) = o;
        }
    }
}

extern "C" void kernel_launch(void* const* d_in, const int* in_sizes, int n_in,
                              void* d_out, int out_size, void* d_ws, size_t ws_size,
                              hipStream_t stream) {
    const float* x     = (const float*)d_in[0];
    const float* cosp  = (const float*)d_in[1];
    const float* sinp  = (const float*)d_in[2];
    const float* Wqkv  = (const float*)d_in[3];
    const float* Wproj = (const float*)d_in[4];
    float* out = (float*)d_out;
    char* ws = (char*)d_ws;
    // workspace layout (96 MB total)
    bf16* xb     = (bf16*)(ws);                          // 16 MB (reused as O after GEMM1)
    bf16* WqkvT  = (bf16*)(ws + (size_t)(16u << 20));    // 24 MB
    bf16* WprojT = (bf16*)(ws + (size_t)(40u << 20));    //  8 MB
    bf16* Qg     = (bf16*)(ws + (size_t)(48u << 20));    // 16 MB
    bf16* Kg     = (bf16*)(ws + (size_t)(64u << 20));    // 16 MB
    f16*  VTg    = (f16*) (ws + (size_t)(80u << 20));    // 16 MB
    bf16* Og     = xb;

    k_prep<<<dim3(8192 + 3072 + 1024), 256, 0, stream>>>(x, Wqkv, Wproj, xb, WqkvT, WprojT);
    k_gemm_qkv<<<dim3(D3_ / 128, NT_ / 256), 512, 0, stream>>>(xb, WqkvT, cosp, sinp, Qg, Kg, VTg);
    k_flash<<<dim3(512), 256, 0, stream>>>(Qg, Kg, VTg, Og);
    k_proj<<<dim3(D_ / 128, NT_ / 256), 512, 0, stream>>>(Og, WprojT, out);
}

// Round 11
// 355.927 us; speedup vs baseline: 1.0398x; 1.0036x over previous
//
#include <hip/hip_runtime.h>
#include <hip/hip_bf16.h>

#define B_  2
#define T_  2048
#define D_  2048
#define H_  16
#define HD_ 128
#define NT_ 4096   // B*T
#define D3_ 6144   // 3*D

typedef __bf16 bf16;
typedef _Float16 f16;
typedef bf16 bf16x2 __attribute__((ext_vector_type(2)));
typedef bf16 bf16x4 __attribute__((ext_vector_type(4)));
typedef bf16 bf16x8 __attribute__((ext_vector_type(8)));
typedef f16  f16x2  __attribute__((ext_vector_type(2)));
typedef f16  f16x4  __attribute__((ext_vector_type(4)));
typedef float floatx4 __attribute__((ext_vector_type(4)));

__device__ __forceinline__ void gl_lds16(const void* g, void* l) {
    __builtin_amdgcn_global_load_lds((const __attribute__((address_space(1))) void*)g,
                                     (__attribute__((address_space(3))) void*)l, 16, 0, 0);
}

// ---------------- fused prep: x->bf16, Wqkv^T->bf16, Wproj^T->bf16 ----------------
__global__ __launch_bounds__(256) void k_prep(const float* __restrict__ x,
                                              const float* __restrict__ Wqkv, const float* __restrict__ Wproj,
                                              bf16* __restrict__ xb, bf16* __restrict__ WqkvT, bf16* __restrict__ WprojT) {
    int blk = blockIdx.x;
    int tid = threadIdx.x;
    if (blk < 8192) {   // x convert: 8192*256*4 = 8M elems
        int i = blk * 256 + tid;
        float4 v = ((const float4*)x)[i];
        bf16x4 o = { (bf16)v.x, (bf16)v.y, (bf16)v.z, (bf16)v.w };
        ((bf16x4*)xb)[i] = o;
        return;
    }
    __shared__ float tile[64][65];
    const float* in; bf16* out; int C, bx;
    if (blk < 8192 + 3072) { bx = blk - 8192; in = Wqkv; out = WqkvT; C = D3_; }
    else                   { bx = blk - 8192 - 3072; in = Wproj; out = WprojT; C = D_; }
    const int R = D_;
    int nbx = C / 64;
    int c0 = (bx % nbx) * 64, r0 = (bx / nbx) * 64;
#pragma unroll
    for (int i = 0; i < 16; i++) {
        int idx = tid + i * 256, r = idx >> 6, c = idx & 63;
        tile[r][c] = in[(size_t)(r0 + r) * C + (c0 + c)];
    }
    __syncthreads();
#pragma unroll
    for (int i = 0; i < 16; i++) {
        int idx = tid + i * 256, r = idx >> 6, c = idx & 63;
        out[(size_t)(c0 + r) * R + (r0 + c)] = (bf16)tile[c][r];
    }
}

// ====== shared GEMM main-loop machinery (256x128 tile, BK=64, 3 buffers, counted vmcnt, ======
// ====== register frag double-buffering: read t+1 frags during t's second MFMA half)     ======
// Per iter t: stage(t+2 -> buf[(t+2)%3]); MFMA half1 (nt 0-1, regs t); vmcnt(6)+barrier
// (lands t+1; t+2 stays in flight); read t+1 frags (overlaps half2); MFMA half2 (nt 2-3).
// Invariants: at iter-t barrier outstanding = t+1(6,oldest)+t+2(6); buf[(t+2)%3]'s last
// reads (tile t-1 frags, iter t-2) precede the iter t-1 barrier all waves passed.
// Tail: t>=30 -> vmcnt(0); t=31 skips reads.

#define G_STAGE(KT, BUFO, JJ) do {                                                      \
        int cI_ = (JJ) * 512 + wid * 64 + lane;                                         \
        const bf16* gsrc_;                                                              \
        if ((JJ) < 4) gsrc_ = Ablk + (size_t)(cI_ >> 3) * D_ + (KT) * 64 + sgch * 8;    \
        else          gsrc_ = Bblk + (size_t)((cI_ >> 3) - 256) * D_ + (KT) * 64 + sgch * 8; \
        gl_lds16(gsrc_, smem + (BUFO) + ((JJ) * 512 + wid * 64) * 8);                   \
    } while (0)

#define G_READ(BUFO, AF, BF) do {                                                       \
        _Pragma("unroll") for (int mt_ = 0; mt_ < 4; mt_++)                             \
        _Pragma("unroll") for (int kc_ = 0; kc_ < 2; kc_++)                             \
            AF[mt_][kc_] = *(const bf16x8*)(smem + (BUFO) + aHalf + coA + mt_ * 1024 + (((kc_ * 4 + quad) ^ (l16 & 7)) * 8)); \
        _Pragma("unroll") for (int nt_ = 0; nt_ < 4; nt_++)                             \
        _Pragma("unroll") for (int kc_ = 0; kc_ < 2; kc_++)                             \
            BF[nt_][kc_] = *(const bf16x8*)(smem + (BUFO) + coB + nt_ * 1024 + (((kc_ * 4 + quad) ^ (l16 & 7)) * 8)); \
    } while (0)

#define G_ITER(T, NXTO, PREO, CAF, CBF, NAF, NBF) do {                                  \
        if ((T) + 2 < 32) {                                                             \
            G_STAGE((T) + 2, (PREO), 0); G_STAGE((T) + 2, (PREO), 1);                   \
            G_STAGE((T) + 2, (PREO), 2); G_STAGE((T) + 2, (PREO), 3);                   \
            G_STAGE((T) + 2, (PREO), 4); G_STAGE((T) + 2, (PREO), 5);                   \
        }                                                                               \
        __builtin_amdgcn_s_setprio(1);                                                  \
        _Pragma("unroll") for (int mt_ = 0; mt_ < 4; mt_++)                             \
        _Pragma("unroll") for (int nt_ = 0; nt_ < 2; nt_++)                             \
        _Pragma("unroll") for (int kc_ = 0; kc_ < 2; kc_++)                             \
            acc[mt_][nt_] = __builtin_amdgcn_mfma_f32_16x16x32_bf16(CAF[mt_][kc_], CBF[nt_][kc_], acc[mt_][nt_], 0, 0, 0); \
        __builtin_amdgcn_s_setprio(0);                                                  \
        if ((T) >= 30) asm volatile("s_waitcnt vmcnt(0)" ::: "memory");                 \
        else           asm volatile("s_waitcnt vmcnt(6)" ::: "memory");                 \
        __builtin_amdgcn_s_barrier();                                                   \
        if ((T) + 1 < 32) { G_READ((NXTO), NAF, NBF); }                                 \
        __builtin_amdgcn_s_setprio(1);                                                  \
        _Pragma("unroll") for (int mt_ = 0; mt_ < 4; mt_++)                             \
        _Pragma("unroll") for (int nt_ = 2; nt_ < 4; nt_++)                             \
        _Pragma("unroll") for (int kc_ = 0; kc_ < 2; kc_++)                             \
            acc[mt_][nt_] = __builtin_amdgcn_mfma_f32_16x16x32_bf16(CAF[mt_][kc_], CBF[nt_][kc_], acc[mt_][nt_], 0, 0, 0); \
        __builtin_amdgcn_s_setprio(0);                                                  \
    } while (0)

#define G_MAINLOOP()                                                                    \
    _Pragma("unroll") for (int j = 0; j < 6; j++) G_STAGE(0, 0, j);                     \
    _Pragma("unroll") for (int j = 0; j < 6; j++) G_STAGE(1, 24576, j);                 \
    asm volatile("s_waitcnt vmcnt(6)" ::: "memory");                                    \
    __builtin_amdgcn_s_barrier();                                                       \
    bf16x8 afA[4][2], bfA[4][2], afB[4][2], bfB[4][2];                                  \
    G_READ(0, afA, bfA);                                                                \
    int b0 = 0, b1 = 24576, b2 = 49152;                                                 \
    for (int t = 0; t < 32; t += 2) {                                                   \
        G_ITER(t,     b1, b2, afA, bfA, afB, bfB);                                      \
        G_ITER(t + 1, b2, b0, afB, bfB, afA, bfA);                                      \
        int tmp_ = b0; b0 = b2; b2 = b1; b1 = tmp_;                                     \
    }

// ---------------- QKV GEMM with fused RoPE + scatter epilogue ----------------
__global__ __launch_bounds__(512, 1) void k_gemm_qkv(const bf16* __restrict__ A, const bf16* __restrict__ Bt,
                                                     const float* __restrict__ cosp, const float* __restrict__ sinp,
                                                     bf16* __restrict__ Qg, bf16* __restrict__ Kg, f16* __restrict__ VTg) {
    __shared__ bf16 smem[3 * 24576];            // 147,456 B
    const int tid = threadIdx.x, wid = tid >> 6, lane = tid & 63;
    const int quad = lane >> 4, l16 = lane & 15;
    const int n0 = blockIdx.x * 128, m0 = blockIdx.y * 256;
    const int wr = (wid >> 1) * 64, wc = (wid & 1) * 64;
    const bf16* Ablk = A + (size_t)m0 * D_;
    const bf16* Bblk = Bt + (size_t)n0 * D_;
    const int sgch = (lane & 7) ^ (lane >> 3);
    const int aHalf = (wid >> 2) * 8192;
    const int rAbase = ((wid >> 1) & 1) * 64;
    const int coA = (rAbase + l16) * 64;
    const int coB = 16384 + (wc + l16) * 64;
    floatx4 acc[4][4] = {};

    G_MAINLOOP()

    bf16* const stage = smem;                   // [256][130]
#pragma unroll
    for (int mt = 0; mt < 4; mt++)
#pragma unroll
        for (int nt = 0; nt < 4; nt++)
#pragma unroll
            for (int r = 0; r < 4; r++)
                stage[(wr + mt * 16 + quad * 4 + r) * 130 + wc + nt * 16 + l16] = (bf16)acc[mt][nt][r];
    __syncthreads();
    const int type = n0 >> 11, h = (n0 & 2047) >> 7;
    const int b = m0 >> 11, t0 = m0 & 2047;
    if (type < 2) {
        bf16* out = (type == 0 ? Qg : Kg) + ((size_t)(b * H_ + h) * T_ + t0) * HD_;
#pragma unroll
        for (int it = 0; it < 32; it++) {
            int idx = it * 512 + tid, tl = idx >> 6, i = idx & 63;
            float c = cosp[(t0 + tl) * 64 + i], s = sinp[(t0 + tl) * 64 + i];
            float x1 = (float)stage[tl * 130 + i], x2 = (float)stage[tl * 130 + 64 + i];
            bf16x2 o = { (bf16)(x1 * c - x2 * s), (bf16)(x1 * s + x2 * c) };
            *(bf16x2*)(out + (size_t)tl * HD_ + 2 * i) = o;
        }
    } else {
        f16* out = VTg + (size_t)(b * H_ + h) * HD_ * T_ + t0;
#pragma unroll
        for (int it = 0; it < 32; it++) {
            int idx = it * 512 + tid, d = idx >> 7, tp = (idx & 127) * 2;
            f16x2 o = { (f16)(float)stage[tp * 130 + d], (f16)(float)stage[(tp + 1) * 130 + d] };
            *(f16x2*)(out + (size_t)d * T_ + tp) = o;
        }
    }
}

// ---------------- proj GEMM: same pipeline, direct-store epilogue ----------------
__global__ __launch_bounds__(512, 1) void k_proj(const bf16* __restrict__ A, const bf16* __restrict__ Bt,
                                                 float* __restrict__ C) {
    __shared__ bf16 smem[3 * 24576];            // 147,456 B
    const int tid = threadIdx.x, wid = tid >> 6, lane = tid & 63;
    const int quad = lane >> 4, l16 = lane & 15;
    const int n0 = blockIdx.x * 128, m0 = blockIdx.y * 256;
    const int wr = (wid >> 1) * 64, wc = (wid & 1) * 64;
    const bf16* Ablk = A + (size_t)m0 * D_;
    const bf16* Bblk = Bt + (size_t)n0 * D_;
    const int sgch = (lane & 7) ^ (lane >> 3);
    const int aHalf = (wid >> 2) * 8192;
    const int rAbase = ((wid >> 1) & 1) * 64;
    const int coA = (rAbase + l16) * 64;
    const int coB = 16384 + (wc + l16) * 64;
    floatx4 acc[4][4] = {};

    G_MAINLOOP()

#pragma unroll
    for (int mt = 0; mt < 4; mt++)
#pragma unroll
        for (int nt = 0; nt < 4; nt++)
#pragma unroll
            for (int r = 0; r < 4; r++) {
                int row = m0 + wr + mt * 16 + quad * 4 + r;
                int col = n0 + wc + nt * 16 + l16;
                C[(size_t)row * D_ + col] = acc[mt][nt][r];
            }
}

// ---------------- Flash attention (R0 serial form) ----------------
__global__ __launch_bounds__(256, 2) void k_flash(const bf16* __restrict__ Qg, const bf16* __restrict__ Kg,
                                                  const f16* __restrict__ VTg, bf16* __restrict__ Og) {
    __shared__ bf16 Ksh[64 * 128];      // K tile: 64 t x 128 d, XOR-swizzled 16B chunks
    __shared__ f16  Vsh[128 * 64];      // V^T tile: 128 d x 64 t, XOR-swizzled
    const int b1 = blockIdx.x;
    const int bh = b1 & 31;
    const int qt = (b1 < 256) ? (15 - (b1 >> 5)) : ((b1 - 256) >> 5);
    const int tid = threadIdx.x, w = tid >> 6, lane = tid & 63;
    const int quad = lane >> 4, l16 = lane & 15;
    const float scale2 = 0.08838834764831845f * 1.4426950408889634f;  // (1/sqrt(128))*log2(e)
    const int wrow = w * 32;
    const bf16* Qb = Qg + ((size_t)bh * T_ + qt * 128) * HD_;
    bf16x8 qf[2][4];
#pragma unroll
    for (int mt = 0; mt < 2; mt++)
#pragma unroll
        for (int kc = 0; kc < 4; kc++)
            qf[mt][kc] = *(const bf16x8*)(Qb + (size_t)(wrow + mt * 16 + l16) * HD_ + kc * 32 + quad * 8);
    floatx4 oaccT[8][2] = {};   // [d-tile][q-tile]: col=l16=query, row=quad*4+r=d
    float lsum[2] = { 0.f, 0.f };
    const int nkt = 2 * (qt + 1);
    for (int kt = 0; kt < nkt; kt++) {
        __syncthreads();
        const bf16* Kt = Kg + ((size_t)bh * T_ + kt * 64) * HD_;
        const f16*  Vt = VTg + (size_t)bh * HD_ * T_ + kt * 64;
#pragma unroll
        for (int i = 0; i < 4; i++) {
            int ch = w * 4 + i;
            {
                int row = ch * 4 + (lane >> 4);
                int c = (lane & 15) ^ (row & 7);
                gl_lds16(Kt + (size_t)row * HD_ + c * 8, Ksh + ch * 512);
            }
            {
                int row = ch * 8 + (lane >> 3);
                int c = (lane & 7) ^ (row & 7);
                gl_lds16(Vt + (size_t)row * T_ + c * 8, Vsh + ch * 512);
            }
        }
        __syncthreads();
        const bool diag = (kt >= 2 * qt);
        f16x4 pf[2][4];
#pragma unroll
        for (int nt = 0; nt < 4; nt++) {
            floatx4 s0 = {}, s1 = {};
#pragma unroll
            for (int kc = 0; kc < 4; kc++) {
                bf16x8 kf = *(const bf16x8*)(Ksh + (nt * 16 + l16) * 128 + (((kc * 4 + quad) ^ (l16 & 7)) * 8));
                s0 = __builtin_amdgcn_mfma_f32_16x16x32_bf16(kf, qf[0][kc], s0, 0, 0, 0);
                s1 = __builtin_amdgcn_mfma_f32_16x16x32_bf16(kf, qf[1][kc], s1, 0, 0, 0);
            }
#pragma unroll
            for (int r = 0; r < 4; r++) {
                float v0 = s0[r] * scale2, v1 = s1[r] * scale2;
                if (diag) {
                    int gk = kt * 64 + nt * 16 + quad * 4 + r;
                    if (gk > qt * 128 + wrow + l16) v0 = -1e30f;
                    if (gk > qt * 128 + wrow + 16 + l16) v1 = -1e30f;
                }
                float p0 = exp2f(v0), p1 = exp2f(v1);
                lsum[0] += p0; lsum[1] += p1;
                pf[0][nt][r] = (f16)p0; pf[1][nt][r] = (f16)p1;
            }
        }
        // O^T += V^T P^T  (16x16x16 f16 MFMA)
#pragma unroll
        for (int nt = 0; nt < 4; nt++)
#pragma unroll
            for (int dt = 0; dt < 8; dt++) {
                int row = dt * 16 + l16;
                f16x4 vf = *(const f16x4*)(Vsh + row * 64 + (((nt * 2 + (quad >> 1)) ^ (row & 7)) * 8) + (quad & 1) * 4);
#pragma unroll
                for (int mt = 0; mt < 2; mt++)
                    oaccT[dt][mt] = __builtin_amdgcn_mfma_f32_16x16x16f16(vf, pf[mt][nt], oaccT[dt][mt], 0, 0, 0);
            }
    }
    // epilogue
    const int b = bh >> 4, h = bh & 15;
    float inv[2];
#pragma unroll
    for (int mt = 0; mt < 2; mt++) {
        float l = lsum[mt];
        l += __shfl_xor(l, 16);
        l += __shfl_xor(l, 32);
        inv[mt] = 1.0f / l;
    }
#pragma unroll
    for (int mt = 0; mt < 2; mt++) {
        int t = qt * 128 + wrow + mt * 16 + l16;
#pragma unroll
        for (int dt = 0; dt < 8; dt++) {
            bf16x4 o;
#pragma unroll
            for (int r = 0; r < 4; r++) o[r] = (bf16)(oaccT[dt][mt][r] * inv[mt]);
            int c = h * HD_ + dt * 16 + quad * 4;
            *(bf16x4*)(Og + (size_t)(b * T_ + t) * D_ + c) = o;
        }
    }
}

extern "C" void kernel_launch(void* const* d_in, const int* in_sizes, int n_in,
                              void* d_out, int out_size, void* d_ws, size_t ws_size,
                              hipStream_t stream) {
    const float* x     = (const float*)d_in[0];
    const float* cosp  = (const float*)d_in[1];
    const float* sinp  = (const float*)d_in[2];
    const float* Wqkv  = (const float*)d_in[3];
    const float* Wproj = (const float*)d_in[4];
    float* out = (float*)d_out;
    char* ws = (char*)d_ws;
    // workspace layout (96 MB total)
    bf16* xb     = (bf16*)(ws);                          // 16 MB (reused as O after GEMM1)
    bf16* WqkvT  = (bf16*)(ws + (size_t)(16u << 20));    // 24 MB
    bf16* WprojT = (bf16*)(ws + (size_t)(40u << 20));    //  8 MB
    bf16* Qg     = (bf16*)(ws + (size_t)(48u << 20));    // 16 MB
    bf16* Kg     = (bf16*)(ws + (size_t)(64u << 20));    // 16 MB
    f16*  VTg    = (f16*) (ws + (size_t)(80u << 20));    // 16 MB
    bf16* Og     = xb;

    k_prep<<<dim3(8192 + 3072 + 1024), 256, 0, stream>>>(x, Wqkv, Wproj, xb, WqkvT, WprojT);
    k_gemm_qkv<<<dim3(D3_ / 128, NT_ / 256), 512, 0, stream>>>(xb, WqkvT, cosp, sinp, Qg, Kg, VTg);
    k_flash<<<dim3(512), 256, 0, stream>>>(Qg, Kg, VTg, Og);
    k_proj<<<dim3(D_ / 128, NT_ / 256), 512, 0, stream>>>(Og, WprojT, out);
}